// Round 1
// baseline (5678.300 us; speedup 1.0000x reference)
//
#include <hip/hip_runtime.h>
#include <hip/hip_bf16.h>

#define NN 100000   // nodes
#define NE 1600000  // edges
#define FF 64       // features
#define NC 10       // classes
#define NL 4        // layers
#define NB 128      // graphs
#define LDST 72     // LDS row stride (bf16 elems), pads 64 -> 72 to break bank pattern

typedef __attribute__((ext_vector_type(8))) short short8;
typedef __attribute__((ext_vector_type(4))) float f32x4;

static __device__ __forceinline__ unsigned short f2bf(float x) {
  // round-to-nearest-even bf16 (bit-level; NaN edge cases irrelevant here)
  unsigned int u = __float_as_uint(x);
  unsigned int r = (u + 0x7fffu + ((u >> 16) & 1u)) >> 16;
  return (unsigned short)r;
}

// ---- scatter: agg[dst] += h[src] over all edges (1 edge-quad / thread) ----
__global__ __launch_bounds__(256) void scatter_kernel(
    const float* __restrict__ h, const int* __restrict__ src,
    const int* __restrict__ dst, float* __restrict__ agg) {
  int tid = blockIdx.x * 256 + threadIdx.x;   // exactly NE*16 threads
  int e = tid >> 4, q = tid & 15;
  int s = src[e], d = dst[e];
  float4 v = *(const float4*)(h + (size_t)s * FF + q * 4);
  float* p = agg + (size_t)d * FF + q * 4;
  unsafeAtomicAdd(p + 0, v.x);
  unsafeAtomicAdd(p + 1, v.y);
  unsafeAtomicAdd(p + 2, v.z);
  unsafeAtomicAdd(p + 3, v.w);
}

// ---- W [k][n] fp32 -> Wt [n][k] bf16 ----
__global__ __launch_bounds__(256) void convw_kernel(
    const float* __restrict__ W, unsigned short* __restrict__ Wt) {
  int t = blockIdx.x * 256 + threadIdx.x;     // 4096 threads
  int k = t >> 6, n = t & 63;
  Wt[n * FF + k] = f2bf(W[k * FF + n]);
}

// ---- out = sigmoid((inA + inB?) @ W), W given transposed bf16 [n][k] ----
// block: 256 thr = 4 waves, 64 rows/block; wave w -> rows w*16..w*16+15
__global__ __launch_bounds__(256) void gemm_sig(
    const float* __restrict__ inA, const float* __restrict__ inB,
    const unsigned short* __restrict__ Wt, float* __restrict__ out, int n_rows) {
  __shared__ unsigned short uL[64 * LDST];
  __shared__ unsigned short wL[64 * LDST];
  int t = threadIdx.x;
  int row0 = blockIdx.x * 64;

  // stage Wt (4096 bf16) into LDS [n][k] stride LDST
  #pragma unroll
  for (int p = 0; p < 4; ++p) {
    int flat = p * 1024 + t * 4;
    int n = flat >> 6, k = flat & 63;
    ushort4 w = *(const ushort4*)(Wt + flat);
    *(ushort4*)(&wL[n * LDST + k]) = w;
  }
  // stage u = inA (+ inB) as bf16 into LDS [r][c] stride LDST
  #pragma unroll
  for (int p = 0; p < 4; ++p) {
    int flat = p * 1024 + t * 4;
    int r = flat >> 6, c = flat & 63;
    int grow = row0 + r;
    float4 a = make_float4(0.f, 0.f, 0.f, 0.f);
    if (grow < n_rows) {
      a = *(const float4*)(inA + (size_t)grow * FF + c);
      if (inB) {
        float4 b = *(const float4*)(inB + (size_t)grow * FF + c);
        a.x += b.x; a.y += b.y; a.z += b.z; a.w += b.w;
      }
    }
    ushort4 u;
    u.x = f2bf(a.x); u.y = f2bf(a.y); u.z = f2bf(a.z); u.w = f2bf(a.w);
    *(ushort4*)(&uL[r * LDST + c]) = u;
  }
  __syncthreads();

  int lane = t & 63, w = t >> 6;
  int m = lane & 15, q = lane >> 4;     // A: m=lane&15, k=q*8+j ; B: n=lane&15
  f32x4 acc[4] = {{0,0,0,0},{0,0,0,0},{0,0,0,0},{0,0,0,0}};
  #pragma unroll
  for (int s = 0; s < 2; ++s) {         // K = 64 = 2 x 32
    short8 a = *(const short8*)(&uL[(w * 16 + m) * LDST + s * 32 + q * 8]);
    #pragma unroll
    for (int c4 = 0; c4 < 4; ++c4) {    // 4 n-chunks of 16
      short8 b = *(const short8*)(&wL[(c4 * 16 + m) * LDST + s * 32 + q * 8]);
      acc[c4] = __builtin_amdgcn_mfma_f32_16x16x32_bf16(a, b, acc[c4], 0, 0, 0);
    }
  }
  // C/D: col = lane&15 (+16*c4), row = q*4 + reg
  #pragma unroll
  for (int c4 = 0; c4 < 4; ++c4) {
    #pragma unroll
    for (int i = 0; i < 4; ++i) {
      int grow = row0 + w * 16 + q * 4 + i;
      if (grow < n_rows) {
        float v = acc[c4][i];
        out[(size_t)grow * FF + c4 * 16 + m] = 1.f / (1.f + __expf(-v));
      }
    }
  }
}

// ---- pool: xr[b] += h[node] (batch sorted; run-length accumulate per wave) ----
__global__ __launch_bounds__(256) void pool_kernel(
    const float* __restrict__ h, const int* __restrict__ batch,
    float* __restrict__ xr) {
  int wave = (blockIdx.x * 256 + threadIdx.x) >> 6;
  int lane = threadIdx.x & 63;
  int r0 = wave * 64;
  if (r0 >= NN) return;
  int r1 = min(r0 + 64, NN);
  float acc = 0.f;
  int cur = batch[r0];
  for (int r = r0; r < r1; ++r) {
    int b = batch[r];
    if (b != cur) {
      unsafeAtomicAdd(&xr[(size_t)cur * FF + lane], acc);
      acc = 0.f; cur = b;
    }
    acc += h[(size_t)r * FF + lane];
  }
  unsafeAtomicAdd(&xr[(size_t)cur * FF + lane], acc);
}

// ---- head: logits = xr @ fc_w^T + fc_b ; out0 = log_softmax, out1 = xr ----
__global__ __launch_bounds__(64) void head_kernel(
    const float* __restrict__ xr, const float* __restrict__ fcw,
    const float* __restrict__ fcb, float* __restrict__ out) {
  int b = blockIdx.x, lane = threadIdx.x;
  float v = xr[(size_t)b * FF + lane];
  out[NB * NC + (size_t)b * FF + lane] = v;     // output 1: xr
  float logit[NC];
  #pragma unroll
  for (int c = 0; c < NC; ++c) {
    float s = v * fcw[c * FF + lane];
    #pragma unroll
    for (int o = 32; o > 0; o >>= 1) s += __shfl_xor(s, o, 64);
    logit[c] = s + fcb[c];
  }
  float mx = logit[0];
  #pragma unroll
  for (int c = 1; c < NC; ++c) mx = fmaxf(mx, logit[c]);
  float se = 0.f;
  #pragma unroll
  for (int c = 0; c < NC; ++c) se += expf(logit[c] - mx);
  float lse = logf(se);
  if (lane < NC) out[b * NC + lane] = logit[lane] - mx - lse;
}

extern "C" void kernel_launch(void* const* d_in, const int* in_sizes, int n_in,
                              void* d_out, int out_size, void* d_ws, size_t ws_size,
                              hipStream_t stream) {
  const float* x     = (const float*)d_in[0];
  const int*   ei    = (const int*)d_in[1];
  const int*   batch = (const int*)d_in[2];
  const float* W1s   = (const float*)d_in[3];
  const float* W2s   = (const float*)d_in[4];
  const float* fcw   = (const float*)d_in[5];
  const float* fcb   = (const float*)d_in[6];
  float* out = (float*)d_out;

  float* h   = (float*)d_ws;                       // NN*FF f32
  float* agg = h + (size_t)NN * FF;                // NN*FF f32
  unsigned short* Wt = (unsigned short*)(agg + (size_t)NN * FF); // FF*FF bf16
  float* xr = (float*)(Wt + FF * FF);              // NB*FF f32

  const int* src = ei;
  const int* dst = ei + NE;

  int gemm_blocks = (NN + 63) / 64;
  for (int l = 0; l < NL; ++l) {
    const float* hin = (l == 0) ? x : h;
    hipMemsetAsync(agg, 0, (size_t)NN * FF * sizeof(float), stream);
    scatter_kernel<<<NE * 16 / 256, 256, 0, stream>>>(hin, src, dst, agg);
    convw_kernel<<<FF * FF / 256, 256, 0, stream>>>(W1s + (size_t)l * FF * FF, Wt);
    gemm_sig<<<gemm_blocks, 256, 0, stream>>>(agg, hin, Wt, agg, NN);
    convw_kernel<<<FF * FF / 256, 256, 0, stream>>>(W2s + (size_t)l * FF * FF, Wt);
    gemm_sig<<<gemm_blocks, 256, 0, stream>>>(agg, nullptr, Wt, h, NN);
  }
  hipMemsetAsync(xr, 0, (size_t)NB * FF * sizeof(float), stream);
  int pool_waves = (NN + 63) / 64;
  int pool_blocks = (pool_waves + 3) / 4;
  pool_kernel<<<pool_blocks, 256, 0, stream>>>(h, batch, xr);
  head_kernel<<<NB, 64, 0, stream>>>(xr, fcw, fcb, out);
}

// Round 2
// 671.273 us; speedup vs baseline: 8.4590x; 8.4590x over previous
//
#include <hip/hip_runtime.h>
#include <hip/hip_bf16.h>

#define NN 100000   // nodes
#define NE 1600000  // edges
#define FF 64       // features
#define NC 10       // classes
#define NL 4        // layers
#define NB 128      // graphs
#define LDST 72     // LDS row stride (bf16), pads 64 -> 72 to break bank pattern
#define SCAN_BLK 1024
#define NBLK_SCAN ((NN + SCAN_BLK - 1) / SCAN_BLK)   // 98

typedef __attribute__((ext_vector_type(8))) short short8;
typedef __attribute__((ext_vector_type(4))) float f32x4;

static __device__ __forceinline__ unsigned short f2bf(float x) {
  unsigned int u = __float_as_uint(x);
  unsigned int r = (u + 0x7fffu + ((u >> 16) & 1u)) >> 16;
  return (unsigned short)r;
}

// ============ CSR build (once per call) ============
__global__ __launch_bounds__(256) void hist_kernel(const int* __restrict__ dst,
                                                   int* __restrict__ deg) {
  int e = blockIdx.x * 256 + threadIdx.x;
  if (e < NE) atomicAdd(&deg[dst[e]], 1);
}

// per-block inclusive scan of deg -> offs[i+1] (block-local), block total -> partials
__global__ __launch_bounds__(256) void scan1(const int* __restrict__ deg,
                                             int* __restrict__ offs,
                                             int* __restrict__ partials) {
  __shared__ int sm[256];
  int t = threadIdx.x;
  int base = blockIdx.x * SCAN_BLK + t * 4;
  int v[4];
  #pragma unroll
  for (int j = 0; j < 4; ++j) {
    int i = base + j;
    v[j] = (i < NN) ? deg[i] : 0;
  }
  int s = v[0] + v[1] + v[2] + v[3];
  sm[t] = s;
  __syncthreads();
  for (int o = 1; o < 256; o <<= 1) {
    int x = (t >= o) ? sm[t - o] : 0;
    __syncthreads();
    sm[t] += x;
    __syncthreads();
  }
  int run = sm[t] - s;   // exclusive prefix of this thread's chunk within block
  #pragma unroll
  for (int j = 0; j < 4; ++j) {
    int i = base + j;
    run += v[j];
    if (i < NN) offs[i + 1] = run;
  }
  if (t == 255) partials[blockIdx.x] = sm[255];
}

// exclusive scan of partials (nblk <= 128), single block
__global__ __launch_bounds__(128) void scan2(int* __restrict__ partials, int nblk) {
  __shared__ int sm[128];
  int t = threadIdx.x;
  int v = (t < nblk) ? partials[t] : 0;
  sm[t] = v;
  __syncthreads();
  for (int o = 1; o < 128; o <<= 1) {
    int x = (t >= o) ? sm[t - o] : 0;
    __syncthreads();
    sm[t] += x;
    __syncthreads();
  }
  if (t < nblk) partials[t] = sm[t] - v;
}

// add block bases; set offs[0]=0
__global__ __launch_bounds__(256) void scan3(int* __restrict__ offs,
                                             const int* __restrict__ partials) {
  int b = blockIdx.x;
  int basev = partials[b];
  int base = b * SCAN_BLK + threadIdx.x * 4;
  #pragma unroll
  for (int j = 0; j < 4; ++j) {
    int i = base + j;
    if (i < NN) offs[i + 1] += basev;
  }
  if (b == 0 && threadIdx.x == 0) offs[0] = 0;
}

__global__ __launch_bounds__(256) void cursor_init(const int* __restrict__ offs,
                                                   int* __restrict__ cursor) {
  int i = blockIdx.x * 256 + threadIdx.x;
  if (i < NN) cursor[i] = offs[i];
}

__global__ __launch_bounds__(256) void fill_kernel(const int* __restrict__ src,
                                                   const int* __restrict__ dst,
                                                   int* __restrict__ cursor,
                                                   int* __restrict__ csr) {
  int e = blockIdx.x * 256 + threadIdx.x;
  if (e >= NE) return;
  int pos = atomicAdd(&cursor[dst[e]], 1);
  csr[pos] = src[e];
}

// ============ per-layer gather: agg[n] = h[n] + sum_{s in in(n)} h[s] ============
// one wave per node, lane = feature; 4 waves (4 nodes) per block
__global__ __launch_bounds__(256) void gather_kernel(
    const float* __restrict__ h, const int* __restrict__ csr,
    const int* __restrict__ offs, float* __restrict__ agg) {
  int node = blockIdx.x * 4 + (threadIdx.x >> 6);
  if (node >= NN) return;
  int lane = threadIdx.x & 63;
  int off = offs[node], end = offs[node + 1];
  float acc = h[(size_t)node * FF + lane];   // self term (eps=0: agg + h)
  int i = off;
  for (; i + 4 <= end; i += 4) {
    int s0 = csr[i], s1 = csr[i + 1], s2 = csr[i + 2], s3 = csr[i + 3];
    float v0 = h[(size_t)s0 * FF + lane];
    float v1 = h[(size_t)s1 * FF + lane];
    float v2 = h[(size_t)s2 * FF + lane];
    float v3 = h[(size_t)s3 * FF + lane];
    acc += (v0 + v1) + (v2 + v3);
  }
  for (; i < end; ++i) acc += h[(size_t)csr[i] * FF + lane];
  agg[(size_t)node * FF + lane] = acc;
}

// ============ W [k][n] fp32 -> Wt [n][k] bf16 ============
__global__ __launch_bounds__(256) void convw_kernel(
    const float* __restrict__ W, unsigned short* __restrict__ Wt) {
  int t = blockIdx.x * 256 + threadIdx.x;
  int k = t >> 6, n = t & 63;
  Wt[n * FF + k] = f2bf(W[k * FF + n]);
}

// ============ out = sigmoid(in @ W), Wt bf16 [n][k]; in-place safe ============
__global__ __launch_bounds__(256) void gemm_sig(
    const float* __restrict__ in, const unsigned short* __restrict__ Wt,
    float* __restrict__ out, int n_rows) {
  __shared__ unsigned short uL[64 * LDST];
  __shared__ unsigned short wL[64 * LDST];
  int t = threadIdx.x;
  int row0 = blockIdx.x * 64;

  #pragma unroll
  for (int p = 0; p < 4; ++p) {
    int flat = p * 1024 + t * 4;
    int n = flat >> 6, k = flat & 63;
    ushort4 w = *(const ushort4*)(Wt + flat);
    *(ushort4*)(&wL[n * LDST + k]) = w;
  }
  #pragma unroll
  for (int p = 0; p < 4; ++p) {
    int flat = p * 1024 + t * 4;
    int r = flat >> 6, c = flat & 63;
    int grow = row0 + r;
    float4 a = make_float4(0.f, 0.f, 0.f, 0.f);
    if (grow < n_rows) a = *(const float4*)(in + (size_t)grow * FF + c);
    ushort4 u;
    u.x = f2bf(a.x); u.y = f2bf(a.y); u.z = f2bf(a.z); u.w = f2bf(a.w);
    *(ushort4*)(&uL[r * LDST + c]) = u;
  }
  __syncthreads();

  int lane = t & 63, w = t >> 6;
  int m = lane & 15, q = lane >> 4;
  f32x4 acc[4] = {{0,0,0,0},{0,0,0,0},{0,0,0,0},{0,0,0,0}};
  #pragma unroll
  for (int s = 0; s < 2; ++s) {
    short8 a = *(const short8*)(&uL[(w * 16 + m) * LDST + s * 32 + q * 8]);
    #pragma unroll
    for (int c4 = 0; c4 < 4; ++c4) {
      short8 b = *(const short8*)(&wL[(c4 * 16 + m) * LDST + s * 32 + q * 8]);
      acc[c4] = __builtin_amdgcn_mfma_f32_16x16x32_bf16(a, b, acc[c4], 0, 0, 0);
    }
  }
  #pragma unroll
  for (int c4 = 0; c4 < 4; ++c4) {
    #pragma unroll
    for (int i = 0; i < 4; ++i) {
      int grow = row0 + w * 16 + q * 4 + i;
      if (grow < n_rows) {
        float v = acc[c4][i];
        out[(size_t)grow * FF + c4 * 16 + m] = 1.f / (1.f + __expf(-v));
      }
    }
  }
}

// ============ pool + head ============
__global__ __launch_bounds__(256) void pool_kernel(
    const float* __restrict__ h, const int* __restrict__ batch,
    float* __restrict__ xr) {
  int wave = (blockIdx.x * 256 + threadIdx.x) >> 6;
  int lane = threadIdx.x & 63;
  int r0 = wave * 64;
  if (r0 >= NN) return;
  int r1 = min(r0 + 64, NN);
  float acc = 0.f;
  int cur = batch[r0];
  for (int r = r0; r < r1; ++r) {
    int b = batch[r];
    if (b != cur) {
      unsafeAtomicAdd(&xr[(size_t)cur * FF + lane], acc);
      acc = 0.f; cur = b;
    }
    acc += h[(size_t)r * FF + lane];
  }
  unsafeAtomicAdd(&xr[(size_t)cur * FF + lane], acc);
}

__global__ __launch_bounds__(64) void head_kernel(
    const float* __restrict__ xr, const float* __restrict__ fcw,
    const float* __restrict__ fcb, float* __restrict__ out) {
  int b = blockIdx.x, lane = threadIdx.x;
  float v = xr[(size_t)b * FF + lane];
  out[NB * NC + (size_t)b * FF + lane] = v;
  float logit[NC];
  #pragma unroll
  for (int c = 0; c < NC; ++c) {
    float s = v * fcw[c * FF + lane];
    #pragma unroll
    for (int o = 32; o > 0; o >>= 1) s += __shfl_xor(s, o, 64);
    logit[c] = s + fcb[c];
  }
  float mx = logit[0];
  #pragma unroll
  for (int c = 1; c < NC; ++c) mx = fmaxf(mx, logit[c]);
  float se = 0.f;
  #pragma unroll
  for (int c = 0; c < NC; ++c) se += expf(logit[c] - mx);
  float lse = logf(se);
  if (lane < NC) out[b * NC + lane] = logit[lane] - mx - lse;
}

extern "C" void kernel_launch(void* const* d_in, const int* in_sizes, int n_in,
                              void* d_out, int out_size, void* d_ws, size_t ws_size,
                              hipStream_t stream) {
  const float* x     = (const float*)d_in[0];
  const int*   ei    = (const int*)d_in[1];
  const int*   batch = (const int*)d_in[2];
  const float* W1s   = (const float*)d_in[3];
  const float* W2s   = (const float*)d_in[4];
  const float* fcw   = (const float*)d_in[5];
  const float* fcb   = (const float*)d_in[6];
  float* out = (float*)d_out;

  // workspace carve-up (all 16B aligned)
  char* p = (char*)d_ws;
  float* h   = (float*)p;                 p += (size_t)NN * FF * 4;     // 25.6 MB
  float* agg = (float*)p;                 p += (size_t)NN * FF * 4;     // 25.6 MB
  int* csr    = (int*)p;                  p += (size_t)NE * 4;          // 6.4 MB
  int* offs   = (int*)p;                  p += (size_t)(NN + 4) * 4;
  int* deg    = (int*)p;                  p += (size_t)NN * 4;          // also cursor
  int* partials = (int*)p;                p += 128 * 4;
  unsigned short* Wt = (unsigned short*)p; p += (size_t)FF * FF * 2;
  float* xr = (float*)p;                  p += (size_t)NB * FF * 4;

  const int* src = ei;
  const int* dst = ei + NE;

  // ---- CSR build (once; reused across layers) ----
  hipMemsetAsync(deg, 0, (size_t)NN * 4, stream);
  hist_kernel<<<(NE + 255) / 256, 256, 0, stream>>>(dst, deg);
  scan1<<<NBLK_SCAN, 256, 0, stream>>>(deg, offs, partials);
  scan2<<<1, 128, 0, stream>>>(partials, NBLK_SCAN);
  scan3<<<NBLK_SCAN, 256, 0, stream>>>(offs, partials);
  cursor_init<<<(NN + 255) / 256, 256, 0, stream>>>(offs, deg);
  fill_kernel<<<(NE + 255) / 256, 256, 0, stream>>>(src, dst, deg, csr);

  // ---- layers ----
  int gemm_blocks = (NN + 63) / 64;
  int gather_blocks = (NN + 3) / 4;
  for (int l = 0; l < NL; ++l) {
    const float* hin = (l == 0) ? x : h;
    gather_kernel<<<gather_blocks, 256, 0, stream>>>(hin, csr, offs, agg);
    convw_kernel<<<FF * FF / 256, 256, 0, stream>>>(W1s + (size_t)l * FF * FF, Wt);
    gemm_sig<<<gemm_blocks, 256, 0, stream>>>(agg, Wt, agg, NN);   // in-place
    convw_kernel<<<FF * FF / 256, 256, 0, stream>>>(W2s + (size_t)l * FF * FF, Wt);
    gemm_sig<<<gemm_blocks, 256, 0, stream>>>(agg, Wt, h, NN);
  }

  hipMemsetAsync(xr, 0, (size_t)NB * FF * 4, stream);
  int pool_blocks = ((NN + 63) / 64 + 3) / 4;
  pool_kernel<<<pool_blocks, 256, 0, stream>>>(h, batch, xr);
  head_kernel<<<NB, 64, 0, stream>>>(xr, fcw, fcb, out);
}

// Round 3
// 620.329 us; speedup vs baseline: 9.1537x; 1.0821x over previous
//
#include <hip/hip_runtime.h>
#include <hip/hip_bf16.h>

#define NN 100000   // nodes
#define NE 1600000  // edges
#define FF 64       // features
#define NC 10       // classes
#define NL 4        // layers
#define NB 128      // graphs
#define LDST 72     // LDS row stride in bf16 elems; 144 B = 9*16B (keeps 16B alignment, breaks bank pattern)
#define SCAN_BLK 1024
#define NBLK_SCAN ((NN + SCAN_BLK - 1) / SCAN_BLK)   // 98

typedef __attribute__((ext_vector_type(8))) short short8;
typedef __attribute__((ext_vector_type(8))) unsigned short ushort8;
typedef __attribute__((ext_vector_type(4))) float f32x4;

static __device__ __forceinline__ unsigned short f2bf(float x) {
  unsigned int u = __float_as_uint(x);
  unsigned int r = (u + 0x7fffu + ((u >> 16) & 1u)) >> 16;
  return (unsigned short)r;
}
static __device__ __forceinline__ float bf2f(unsigned short u) {
  return __uint_as_float(((unsigned int)u) << 16);
}

// ============ x (f32) -> xb (bf16) ============
__global__ __launch_bounds__(256) void x2bf_kernel(const float* __restrict__ x,
                                                   unsigned short* __restrict__ xb) {
  int t = blockIdx.x * 256 + threadIdx.x;   // NN*FF/8 threads
  size_t base = (size_t)t * 8;
  float4 a = *(const float4*)(x + base);
  float4 b = *(const float4*)(x + base + 4);
  ushort8 u;
  u[0] = f2bf(a.x); u[1] = f2bf(a.y); u[2] = f2bf(a.z); u[3] = f2bf(a.w);
  u[4] = f2bf(b.x); u[5] = f2bf(b.y); u[6] = f2bf(b.z); u[7] = f2bf(b.w);
  *(ushort8*)(xb + base) = u;
}

// ============ all W [k][n] f32 -> Wt [mat][n][k] bf16; mats: l*2 = W1s[l], l*2+1 = W2s[l] ============
__global__ __launch_bounds__(256) void convw_all(const float* __restrict__ W1s,
                                                 const float* __restrict__ W2s,
                                                 unsigned short* __restrict__ Wt) {
  int t = blockIdx.x * 256 + threadIdx.x;   // 2*NL*FF*FF = 32768 threads
  int mat = t >> 12, idx = t & 4095;
  int k = idx >> 6, n = idx & 63;
  int l = mat >> 1;
  const float* W = (mat & 1) ? (W2s + (size_t)l * FF * FF) : (W1s + (size_t)l * FF * FF);
  Wt[(size_t)mat * FF * FF + n * FF + k] = f2bf(W[k * FF + n]);
}

// ============ CSR build (once per call) ============
__global__ __launch_bounds__(256) void hist_kernel(const int* __restrict__ dst,
                                                   int* __restrict__ deg) {
  int e = blockIdx.x * 256 + threadIdx.x;
  if (e < NE) atomicAdd(&deg[dst[e]], 1);
}

__global__ __launch_bounds__(256) void scan1(const int* __restrict__ deg,
                                             int* __restrict__ offs,
                                             int* __restrict__ partials) {
  __shared__ int sm[256];
  int t = threadIdx.x;
  int base = blockIdx.x * SCAN_BLK + t * 4;
  int v[4];
  #pragma unroll
  for (int j = 0; j < 4; ++j) {
    int i = base + j;
    v[j] = (i < NN) ? deg[i] : 0;
  }
  int s = v[0] + v[1] + v[2] + v[3];
  sm[t] = s;
  __syncthreads();
  for (int o = 1; o < 256; o <<= 1) {
    int x = (t >= o) ? sm[t - o] : 0;
    __syncthreads();
    sm[t] += x;
    __syncthreads();
  }
  int run = sm[t] - s;
  #pragma unroll
  for (int j = 0; j < 4; ++j) {
    int i = base + j;
    run += v[j];
    if (i < NN) offs[i + 1] = run;
  }
  if (t == 255) partials[blockIdx.x] = sm[255];
}

__global__ __launch_bounds__(128) void scan2(int* __restrict__ partials, int nblk) {
  __shared__ int sm[128];
  int t = threadIdx.x;
  int v = (t < nblk) ? partials[t] : 0;
  sm[t] = v;
  __syncthreads();
  for (int o = 1; o < 128; o <<= 1) {
    int x = (t >= o) ? sm[t - o] : 0;
    __syncthreads();
    sm[t] += x;
    __syncthreads();
  }
  if (t < nblk) partials[t] = sm[t] - v;
}

__global__ __launch_bounds__(256) void scan3(int* __restrict__ offs,
                                             const int* __restrict__ partials) {
  int b = blockIdx.x;
  int basev = partials[b];
  int base = b * SCAN_BLK + threadIdx.x * 4;
  #pragma unroll
  for (int j = 0; j < 4; ++j) {
    int i = base + j;
    if (i < NN) offs[i + 1] += basev;
  }
  if (b == 0 && threadIdx.x == 0) offs[0] = 0;
}

__global__ __launch_bounds__(256) void cursor_init(const int* __restrict__ offs,
                                                   int* __restrict__ cursor) {
  int i = blockIdx.x * 256 + threadIdx.x;
  if (i < NN) cursor[i] = offs[i];
}

__global__ __launch_bounds__(256) void fill_kernel(const int* __restrict__ src,
                                                   const int* __restrict__ dst,
                                                   int* __restrict__ cursor,
                                                   int* __restrict__ csr) {
  int e = blockIdx.x * 256 + threadIdx.x;
  if (e >= NE) return;
  int pos = atomicAdd(&cursor[dst[e]], 1);
  csr[pos] = src[e];
}

// ============ gather: aggb[n] = hb[n] + sum_{s in in(n)} hb[s]  (bf16 in/out, f32 accum) ============
__global__ __launch_bounds__(256) void gather_kernel(
    const unsigned short* __restrict__ hb, const int* __restrict__ csr,
    const int* __restrict__ offs, unsigned short* __restrict__ aggb) {
  int node = blockIdx.x * 4 + (threadIdx.x >> 6);
  if (node >= NN) return;
  int lane = threadIdx.x & 63;
  int off = offs[node], end = offs[node + 1];
  float acc = bf2f(hb[(size_t)node * FF + lane]);   // self term
  int i = off;
  for (; i + 4 <= end; i += 4) {
    int s0 = csr[i], s1 = csr[i + 1], s2 = csr[i + 2], s3 = csr[i + 3];
    float v0 = bf2f(hb[(size_t)s0 * FF + lane]);
    float v1 = bf2f(hb[(size_t)s1 * FF + lane]);
    float v2 = bf2f(hb[(size_t)s2 * FF + lane]);
    float v3 = bf2f(hb[(size_t)s3 * FF + lane]);
    acc += (v0 + v1) + (v2 + v3);
  }
  for (; i < end; ++i) acc += bf2f(hb[(size_t)csr[i] * FF + lane]);
  aggb[(size_t)node * FF + lane] = f2bf(acc);
}

// ============ fused MLP: hb = sig(sig(aggb @ W1) @ W2), all bf16 storage ============
// block = 256 thr (4 waves), 64 rows; intermediate lives in LDS only
__global__ __launch_bounds__(256) void mlp2_kernel(
    const unsigned short* __restrict__ aggb, const unsigned short* __restrict__ Wt,
    unsigned short* __restrict__ hb, int n_rows) {
  __shared__ unsigned short uL[64 * LDST];   // input rows
  __shared__ unsigned short vL[64 * LDST];   // intermediate rows
  __shared__ unsigned short w1L[64 * LDST];
  __shared__ unsigned short w2L[64 * LDST];
  int t = threadIdx.x;
  int row0 = blockIdx.x * 64;

  // stage weights (4096 bf16 each), already [n][k]
  #pragma unroll
  for (int p = 0; p < 2; ++p) {
    int flat = p * 2048 + t * 8;
    int n = flat >> 6, k = flat & 63;
    *(ushort8*)(&w1L[n * LDST + k]) = *(const ushort8*)(Wt + flat);
    *(ushort8*)(&w2L[n * LDST + k]) = *(const ushort8*)(Wt + FF * FF + flat);
  }
  // stage input rows (bf16 passthrough)
  #pragma unroll
  for (int p = 0; p < 2; ++p) {
    int flat = p * 2048 + t * 8;
    int r = flat >> 6, c = flat & 63;
    int grow = row0 + r;
    ushort8 v = {0, 0, 0, 0, 0, 0, 0, 0};
    if (grow < n_rows) v = *(const ushort8*)(aggb + (size_t)grow * FF + c);
    *(ushort8*)(&uL[r * LDST + c]) = v;
  }
  __syncthreads();

  int lane = t & 63, w = t >> 6;
  int m = lane & 15, q = lane >> 4;

  // GEMM1: vL = sigmoid(uL @ W1)
  f32x4 acc[4] = {{0,0,0,0},{0,0,0,0},{0,0,0,0},{0,0,0,0}};
  #pragma unroll
  for (int s = 0; s < 2; ++s) {
    short8 a = *(const short8*)(&uL[(w * 16 + m) * LDST + s * 32 + q * 8]);
    #pragma unroll
    for (int c4 = 0; c4 < 4; ++c4) {
      short8 b = *(const short8*)(&w1L[(c4 * 16 + m) * LDST + s * 32 + q * 8]);
      acc[c4] = __builtin_amdgcn_mfma_f32_16x16x32_bf16(a, b, acc[c4], 0, 0, 0);
    }
  }
  #pragma unroll
  for (int c4 = 0; c4 < 4; ++c4) {
    #pragma unroll
    for (int i = 0; i < 4; ++i) {
      int r = w * 16 + q * 4 + i;                    // C/D: row = q*4+reg, col = c4*16+m
      float sgv = 1.f / (1.f + __expf(-acc[c4][i]));
      vL[r * LDST + c4 * 16 + m] = f2bf(sgv);
    }
  }
  __syncthreads();

  // GEMM2: hb = sigmoid(vL @ W2)
  f32x4 acc2[4] = {{0,0,0,0},{0,0,0,0},{0,0,0,0},{0,0,0,0}};
  #pragma unroll
  for (int s = 0; s < 2; ++s) {
    short8 a = *(const short8*)(&vL[(w * 16 + m) * LDST + s * 32 + q * 8]);
    #pragma unroll
    for (int c4 = 0; c4 < 4; ++c4) {
      short8 b = *(const short8*)(&w2L[(c4 * 16 + m) * LDST + s * 32 + q * 8]);
      acc2[c4] = __builtin_amdgcn_mfma_f32_16x16x32_bf16(a, b, acc2[c4], 0, 0, 0);
    }
  }
  #pragma unroll
  for (int c4 = 0; c4 < 4; ++c4) {
    #pragma unroll
    for (int i = 0; i < 4; ++i) {
      int grow = row0 + w * 16 + q * 4 + i;
      if (grow < n_rows) {
        float sgv = 1.f / (1.f + __expf(-acc2[c4][i]));
        hb[(size_t)grow * FF + c4 * 16 + m] = f2bf(sgv);
      }
    }
  }
}

// ============ pool: xr[b] += h[node] (batch sorted; run-length per wave) ============
__global__ __launch_bounds__(256) void pool_kernel(
    const unsigned short* __restrict__ hb, const int* __restrict__ batch,
    float* __restrict__ xr) {
  int wave = (blockIdx.x * 256 + threadIdx.x) >> 6;
  int lane = threadIdx.x & 63;
  int r0 = wave * 64;
  if (r0 >= NN) return;
  int r1 = min(r0 + 64, NN);
  float acc = 0.f;
  int cur = batch[r0];
  for (int r = r0; r < r1; ++r) {
    int b = batch[r];
    if (b != cur) {
      unsafeAtomicAdd(&xr[(size_t)cur * FF + lane], acc);
      acc = 0.f; cur = b;
    }
    acc += bf2f(hb[(size_t)r * FF + lane]);
  }
  unsafeAtomicAdd(&xr[(size_t)cur * FF + lane], acc);
}

// ============ head ============
__global__ __launch_bounds__(64) void head_kernel(
    const float* __restrict__ xr, const float* __restrict__ fcw,
    const float* __restrict__ fcb, float* __restrict__ out) {
  int b = blockIdx.x, lane = threadIdx.x;
  float v = xr[(size_t)b * FF + lane];
  out[NB * NC + (size_t)b * FF + lane] = v;
  float logit[NC];
  #pragma unroll
  for (int c = 0; c < NC; ++c) {
    float s = v * fcw[c * FF + lane];
    #pragma unroll
    for (int o = 32; o > 0; o >>= 1) s += __shfl_xor(s, o, 64);
    logit[c] = s + fcb[c];
  }
  float mx = logit[0];
  #pragma unroll
  for (int c = 1; c < NC; ++c) mx = fmaxf(mx, logit[c]);
  float se = 0.f;
  #pragma unroll
  for (int c = 0; c < NC; ++c) se += expf(logit[c] - mx);
  float lse = logf(se);
  if (lane < NC) out[b * NC + lane] = logit[lane] - mx - lse;
}

extern "C" void kernel_launch(void* const* d_in, const int* in_sizes, int n_in,
                              void* d_out, int out_size, void* d_ws, size_t ws_size,
                              hipStream_t stream) {
  const float* x     = (const float*)d_in[0];
  const int*   ei    = (const int*)d_in[1];
  const int*   batch = (const int*)d_in[2];
  const float* W1s   = (const float*)d_in[3];
  const float* W2s   = (const float*)d_in[4];
  const float* fcw   = (const float*)d_in[5];
  const float* fcb   = (const float*)d_in[6];
  float* out = (float*)d_out;

  char* p = (char*)d_ws;
  unsigned short* xb   = (unsigned short*)p; p += (size_t)NN * FF * 2;  // 12.8 MB
  unsigned short* hb   = (unsigned short*)p; p += (size_t)NN * FF * 2;  // 12.8 MB
  unsigned short* aggb = (unsigned short*)p; p += (size_t)NN * FF * 2;  // 12.8 MB
  int* csr      = (int*)p;  p += (size_t)NE * 4;                        // 6.4 MB
  int* offs     = (int*)p;  p += (size_t)(NN + 4) * 4;
  int* deg      = (int*)p;  p += (size_t)NN * 4;                        // also cursor
  int* partials = (int*)p;  p += 128 * 4;
  unsigned short* Wtall = (unsigned short*)p; p += (size_t)2 * NL * FF * FF * 2;
  float* xr     = (float*)p; p += (size_t)NB * FF * 4;

  const int* src = ei;
  const int* dst = ei + NE;

  // ---- prep: x->bf16, all weights -> transposed bf16 ----
  x2bf_kernel<<<NN * FF / (256 * 8), 256, 0, stream>>>(x, xb);
  convw_all<<<2 * NL * FF * FF / 256, 256, 0, stream>>>(W1s, W2s, Wtall);

  // ---- CSR build ----
  hipMemsetAsync(deg, 0, (size_t)NN * 4, stream);
  hist_kernel<<<(NE + 255) / 256, 256, 0, stream>>>(dst, deg);
  scan1<<<NBLK_SCAN, 256, 0, stream>>>(deg, offs, partials);
  scan2<<<1, 128, 0, stream>>>(partials, NBLK_SCAN);
  scan3<<<NBLK_SCAN, 256, 0, stream>>>(offs, partials);
  cursor_init<<<(NN + 255) / 256, 256, 0, stream>>>(offs, deg);
  fill_kernel<<<(NE + 255) / 256, 256, 0, stream>>>(src, dst, deg, csr);

  // ---- layers ----
  int gemm_blocks = (NN + 63) / 64;
  int gather_blocks = (NN + 3) / 4;
  for (int l = 0; l < NL; ++l) {
    const unsigned short* hin = (l == 0) ? xb : hb;
    gather_kernel<<<gather_blocks, 256, 0, stream>>>(hin, csr, offs, aggb);
    mlp2_kernel<<<gemm_blocks, 256, 0, stream>>>(aggb, Wtall + (size_t)l * 2 * FF * FF, hb, NN);
  }

  hipMemsetAsync(xr, 0, (size_t)NB * FF * 4, stream);
  int pool_blocks = ((NN + 63) / 64 + 3) / 4;
  pool_kernel<<<pool_blocks, 256, 0, stream>>>(hb, batch, xr);
  head_kernel<<<NB, 64, 0, stream>>>(xr, fcw, fcb, out);
}